// Round 21
// baseline (165.552 us; speedup 1.0000x reference)
//
#include <hip/hip_runtime.h>

// LinearAttention on MI355X — round 21 = round 20 with gemm_outrms LDS cut to
// exactly 80KB (rsum/invr aliased into the dead As region; trans over all)
// -> 2 blocks/CU so the store/transpose epilogue overlaps another block's GEMM.
// ws: S1=0: xnT -> P(8MB) + M@+8M | S2=33.5M: qT | S3=67.1M: kv
//     E=134217728: wbf(1.5M) | woutbf@135790592 | sden@136314880 (16KB)

typedef unsigned short u16;
typedef __attribute__((ext_vector_type(8))) short short8;
typedef __attribute__((ext_vector_type(4))) short short4_t;
typedef __attribute__((ext_vector_type(4))) float f32x4;

static constexpr size_t XN_B = (size_t)512 * 4096;
static constexpr size_t KV_B = (size_t)1024 * 4096;
static constexpr float SQRT512 = 22.62741699796952f;

typedef const __attribute__((address_space(1))) unsigned int gu32;
typedef __attribute__((address_space(3))) unsigned int lu32;

__device__ __forceinline__ float b2f(u16 u){
  union { unsigned u; float f; } x; x.u = ((unsigned)u) << 16; return x.f;
}
__device__ __forceinline__ u16 f2b(float f){
  union { float f; unsigned u; } x; x.f = f;
  unsigned r = x.u + 0x7FFFu + ((x.u >> 16) & 1u);   // RNE
  return (u16)(r >> 16);
}
__device__ __forceinline__ void gl16(const u16* g, u16* l){
  __builtin_amdgcn_global_load_lds((gu32*)g, (lu32*)l, 16, 0, 0);
}

// ---- kprep: blocks 0-1023 convert weights (g1 folded into wqkv; blocks 0-15
//      also zero sden); blocks 1024-2047 fused rms1, f32x4-vectorized
__global__ __launch_bounds__(256)
void kprep(const float* __restrict__ wqkv, const float* __restrict__ wout,
           const float* __restrict__ g1, u16* __restrict__ dq, u16* __restrict__ dw,
           const float* __restrict__ x, u16* __restrict__ xnT,
           float* __restrict__ sden){
  __shared__ u16 lt[32][514];
  __shared__ float red4[256][4];
  __shared__ float invs[32];
  int bid = blockIdx.x;
  int t = threadIdx.x;
  if (bid < 1024){
    if (bid < 16) sden[bid * 256 + t] = 0.f;
    size_t i = ((size_t)bid * 256 + t) * 4;
    short4_t o;
    if (i < (size_t)786432){
      f32x4 v = *(const f32x4*)(wqkv + i);
      int c = (int)(i & 511);
      #pragma unroll
      for (int j = 0; j < 4; j++) o[j] = (short)f2b(v[j] * g1[c + j] * SQRT512);
      *(short4_t*)(dq + i) = o;
    } else {
      size_t off = i - 786432;
      f32x4 v = *(const f32x4*)(wout + off);
      #pragma unroll
      for (int j = 0; j < 4; j++) o[j] = (short)f2b(v[j]);
      *(short4_t*)(dw + off) = o;
    }
    return;
  }
  int pg0 = (bid - 1024) * 32;
  int b = pg0 >> 12, p0 = pg0 & 4095;
  int pxg = (t & 7) * 4;
  int chunk = t >> 3;
  const float* xp = x + (size_t)b * XN_B + p0 + pxg;
  f32x4 s = {0.f, 0.f, 0.f, 0.f};
  #pragma unroll 4
  for (int c = chunk * 16; c < chunk * 16 + 16; ++c){
    f32x4 v = *(const f32x4*)(xp + (size_t)c * 4096);
    #pragma unroll
    for (int j = 0; j < 4; j++){
      lt[pxg + j][c] = f2b(v[j]);
      s[j] += v[j] * v[j];
    }
  }
  *(f32x4*)red4[t] = s;
  __syncthreads();
  if (t < 32){
    int pg = t >> 2, pe = t & 3;
    float sum = 0.f;
    #pragma unroll
    for (int ch = 0; ch < 32; ch++) sum += red4[ch * 8 + pg][pe];
    invs[t] = rsqrtf(sum + 1e-12f);
  }
  __syncthreads();
  int px2 = t >> 3, c0 = (t & 7) * 8;
  float iv = invs[px2];
  u16* dst = xnT + (size_t)(pg0 + px2) * 512;
  #pragma unroll
  for (int j = 0; j < 8; j++){
    int c = c0 + j * 64;
    short8 o;
    #pragma unroll
    for (int e = 0; e < 8; e++) o[e] = (short)f2b(b2f(lt[px2][c + e]) * iv);
    *(short8*)(dst + c) = o;
  }
}

// ---- gemm_kv: kv_b = Wkv @ xn_b (M=1024,N=4096,K=512). r5/r12 exact:
// 128^2 tile, BK=64 dbuf, counted vmcnt(8), 8-chunk XOR swizzle.
__global__ __launch_bounds__(256)
void gemm_kv(const u16* __restrict__ Wkv, const u16* __restrict__ xnT,
             u16* __restrict__ kvb)
{
  constexpr int NT = 8;                 // K=512 / BK=64
  const int z = blockIdx.z;
  const u16* A  = Wkv;
  const u16* BT = xnT + (size_t)z * XN_B;
  u16* C = kvb + (size_t)z * KV_B;
  const int m0 = blockIdx.y * 128, n0 = blockIdx.x * 128;
  __shared__ u16 As[2][128 * 64];
  __shared__ u16 Bs[2][128 * 64];
  const int tid = threadIdx.x;
  const int srow0 = tid >> 3;           // 32 rows per staging group
  const int schunk = tid & 7;           // 16B chunk slot within 128B row
  const int lane = tid & 63, wid = tid >> 6;
  const int wr = (wid >> 1) * 64, wc = (wid & 1) * 64;
  const int fr = lane & 15, fq = lane >> 4;
  f32x4 acc[4][4] = {};

  auto STAGE = [&](int s, int t){
    const int k0 = t * 64;
    #pragma unroll
    for (int r = 0; r < 4; r++){
      int row = r * 32 + srow0;
      int gj = (schunk ^ (row & 7)) * 8;
      gl16(A  + (size_t)(m0 + row) * 512 + k0 + gj, &As[s][0] + r * 2048 + tid * 8);
      gl16(BT + (size_t)(n0 + row) * 512 + k0 + gj, &Bs[s][0] + r * 2048 + tid * 8);
    }
  };

  STAGE(0, 0);
  int cur = 0;
  for (int t = 0; t < NT; t++){
    if (t + 1 < NT){
      STAGE(cur ^ 1, t + 1);
      asm volatile("s_waitcnt vmcnt(8)" ::: "memory");
    } else {
      asm volatile("s_waitcnt vmcnt(0)" ::: "memory");
    }
    __builtin_amdgcn_s_barrier();
    __builtin_amdgcn_sched_barrier(0);
    #pragma unroll
    for (int ks = 0; ks < 2; ks++){
      short8 a[4], b[4];
      #pragma unroll
      for (int i = 0; i < 4; i++){
        int ra = wr + i * 16 + fr;
        a[i] = *(const short8*)(&As[cur][0] + ra * 64 + ((ks * 4 + fq) ^ (ra & 7)) * 8);
        int rb = wc + i * 16 + fr;
        b[i] = *(const short8*)(&Bs[cur][0] + rb * 64 + ((ks * 4 + fq) ^ (rb & 7)) * 8);
      }
      #pragma unroll
      for (int i = 0; i < 4; i++)
        #pragma unroll
        for (int j = 0; j < 4; j++)
          acc[i][j] = __builtin_amdgcn_mfma_f32_16x16x32_bf16(a[i], b[j], acc[i][j], 0, 0, 0);
    }
    __builtin_amdgcn_sched_barrier(0);
    __builtin_amdgcn_s_barrier();
    cur ^= 1;
  }

  #pragma unroll
  for (int i = 0; i < 4; i++)
    #pragma unroll
    for (int j = 0; j < 4; j++)
      #pragma unroll
      for (int e = 0; e < 4; e++){
        int row = m0 + wr + i * 16 + fq * 4 + e;
        int col = n0 + wc + j * 16 + fr;
        C[(size_t)row * 4096 + col] = f2b(acc[i][j][e]);
      }
}

// ---- gemm_q: qT = softmax_d(xnT @ Wq^T)/8. r10 exact: 256^2, 8 waves,
// BK=32 dbuf, vmcnt(4), chunk-XOR swizzle, setprio.
__global__ __launch_bounds__(512)
void gemm_q(const u16* __restrict__ xnT, const u16* __restrict__ wq,
            u16* __restrict__ qT)
{
  constexpr int NT = 16;
  const u16* A  = xnT;
  const u16* BT = wq;
  const int m0 = blockIdx.y * 256, n0 = blockIdx.x * 256;
  __shared__ u16 As[2][256 * 32];
  __shared__ u16 Bs[2][256 * 32];
  const int tid = threadIdx.x;
  const int lane = tid & 63, wid = tid >> 6;
  const int wr = (wid >> 2) * 128, wc = (wid & 3) * 64;
  const int fr = lane & 15, fq = lane >> 4;
  const int srow = tid >> 2;
  const int sslot = tid & 3;
  f32x4 acc[8][4] = {};

  auto STAGE = [&](int s, int t){
    const int k0 = t * 32;
    #pragma unroll
    for (int r = 0; r < 2; r++){
      int row = r * 128 + srow;
      int gj = (sslot ^ ((row >> 1) & 3)) * 8;
      gl16(A  + (size_t)(m0 + row) * 512 + k0 + gj, &As[s][0] + r * 4096 + tid * 8);
      gl16(BT + (size_t)(n0 + row) * 512 + k0 + gj, &Bs[s][0] + r * 4096 + tid * 8);
    }
  };

  STAGE(0, 0);
  int cur = 0;
  for (int t = 0; t < NT; t++){
    if (t + 1 < NT){
      STAGE(cur ^ 1, t + 1);
      asm volatile("s_waitcnt vmcnt(4)" ::: "memory");
    } else {
      asm volatile("s_waitcnt vmcnt(0)" ::: "memory");
    }
    __builtin_amdgcn_s_barrier();
    __builtin_amdgcn_sched_barrier(0);
    short8 a[8], b[4];
    #pragma unroll
    for (int i = 0; i < 8; i++){
      int ra = wr + i * 16 + fr;
      a[i] = *(const short8*)(&As[cur][0] + ra * 32 + ((fq ^ ((ra >> 1) & 3)) * 8));
    }
    #pragma unroll
    for (int j = 0; j < 4; j++){
      int rb = wc + j * 16 + fr;
      b[j] = *(const short8*)(&Bs[cur][0] + rb * 32 + ((fq ^ ((rb >> 1) & 3)) * 8));
    }
    __builtin_amdgcn_s_setprio(1);
    #pragma unroll
    for (int i = 0; i < 8; i++)
      #pragma unroll
      for (int j = 0; j < 4; j++)
        acc[i][j] = __builtin_amdgcn_mfma_f32_16x16x32_bf16(a[i], b[j], acc[i][j], 0, 0, 0);
    __builtin_amdgcn_s_setprio(0);
    __builtin_amdgcn_sched_barrier(0);
    __builtin_amdgcn_s_barrier();
    cur ^= 1;
  }

  #pragma unroll
  for (int i = 0; i < 8; i++)
    #pragma unroll
    for (int e = 0; e < 4; e++){
      float mx = fmaxf(fmaxf(acc[i][0][e], acc[i][1][e]),
                       fmaxf(acc[i][2][e], acc[i][3][e]));
      mx = fmaxf(mx, __shfl_xor(mx, 1));
      mx = fmaxf(mx, __shfl_xor(mx, 2));
      mx = fmaxf(mx, __shfl_xor(mx, 4));
      mx = fmaxf(mx, __shfl_xor(mx, 8));
      float p0 = __expf(acc[i][0][e] - mx);
      float p1 = __expf(acc[i][1][e] - mx);
      float p2 = __expf(acc[i][2][e] - mx);
      float p3 = __expf(acc[i][3][e] - mx);
      float s = p0 + p1 + p2 + p3;
      s += __shfl_xor(s, 1);
      s += __shfl_xor(s, 2);
      s += __shfl_xor(s, 4);
      s += __shfl_xor(s, 8);
      float r = 1.f / (s * 8.0f);
      acc[i][0][e] = p0 * r; acc[i][1][e] = p1 * r;
      acc[i][2][e] = p2 * r; acc[i][3][e] = p3 * r;
    }
  #pragma unroll
  for (int i = 0; i < 8; i++)
    #pragma unroll
    for (int j = 0; j < 4; j++)
      #pragma unroll
      for (int e = 0; e < 4; e++){
        int row = m0 + wr + i * 16 + fq * 4 + e;
        int col = n0 + wc + j * 16 + fr;
        qT[(size_t)row * 512 + col] = f2b(acc[i][j][e]);
      }
}

// ---- fused out2 GEMM + rms2; LDS cut to EXACTLY 80KB -> 2 blocks/CU.
// rsum/invr alias the As region (dead after final MFMA barrier); trans
// aliases the whole buffer (rsum/invr consumed before first trans write).
__global__ __launch_bounds__(512)
void gemm_outrms(const u16* __restrict__ qT, const u16* __restrict__ Mb,
                 const float* __restrict__ bias, const float* __restrict__ g2,
                 float* __restrict__ out)
{
  constexpr int NT = 16;
  const int mt = blockIdx.x, z = blockIdx.y;
  const u16* A  = qT + (size_t)z * 4096 * 512;
  const u16* BT = Mb + (size_t)z * 262144;
  const int m0 = mt * 128;

  __shared__ char smem[81920] __attribute__((aligned(16)));
  u16*   As    = (u16*)smem;                 // [2][128*32] = 16384 B (GEMM)
  u16*   Bs    = (u16*)(smem + 16384);       // [2][512*32] = 65536 B (GEMM)
  float* rsum  = (float*)smem;               // [128][4] = 2048 B  (post-GEMM)
  float* invr  = (float*)(smem + 2048);      // [128]    = 512 B   (post-GEMM)
  float* trans = (float*)smem;               // [512][40] = 81884 B (post-norm)

  const int tid = threadIdx.x;
  const int lane = tid & 63, wid = tid >> 6;
  const int wr = (wid >> 2) * 64;
  const int wc = (wid & 3) * 128;
  const int fr = lane & 15, fq = lane >> 4;
  const int srow = tid >> 2, schunk = tid & 3;
  f32x4 acc[4][8] = {};

  auto STAGE = [&](int s, int t){
    const int k0 = t * 32;
    {
      int gj = (schunk ^ ((srow >> 1) & 3)) * 8;
      gl16(A + (size_t)(m0 + srow) * 512 + k0 + gj, As + s * 4096 + tid * 8);
    }
    #pragma unroll
    for (int r = 0; r < 4; r++){
      int row = r * 128 + srow;
      int gj = (schunk ^ ((row >> 1) & 3)) * 8;
      gl16(BT + (size_t)row * 512 + k0 + gj, Bs + s * 16384 + r * 4096 + tid * 8);
    }
  };

  STAGE(0, 0);
  int cur = 0;
  for (int t = 0; t < NT; t++){
    if (t + 1 < NT){
      STAGE(cur ^ 1, t + 1);
      asm volatile("s_waitcnt vmcnt(5)" ::: "memory");
    } else {
      asm volatile("s_waitcnt vmcnt(0)" ::: "memory");
    }
    __builtin_amdgcn_s_barrier();
    __builtin_amdgcn_sched_barrier(0);
    short8 a[4], b[8];
    #pragma unroll
    for (int i = 0; i < 4; i++){
      int ra = wr + i * 16 + fr;
      a[i] = *(const short8*)(As + cur * 4096 + ra * 32 + ((fq ^ ((ra >> 1) & 3)) * 8));
    }
    #pragma unroll
    for (int j = 0; j < 8; j++){
      int rb = wc + j * 16 + fr;
      b[j] = *(const short8*)(Bs + cur * 16384 + rb * 32 + ((fq ^ ((rb >> 1) & 3)) * 8));
    }
    #pragma unroll
    for (int i = 0; i < 4; i++)
      #pragma unroll
      for (int j = 0; j < 8; j++)
        acc[i][j] = __builtin_amdgcn_mfma_f32_16x16x32_bf16(a[i], b[j], acc[i][j], 0, 0, 0);
    __builtin_amdgcn_sched_barrier(0);
    __builtin_amdgcn_s_barrier();
    cur ^= 1;
  }

  // epilogue: bias + row sumsq; rsum/invr live in the (now dead) As region
  float bcol[8], gcol[8];
  #pragma unroll
  for (int j = 0; j < 8; j++){
    int col = wc + j * 16 + fr;
    bcol[j] = bias[col];
    gcol[j] = g2[col] * SQRT512;
  }
  #pragma unroll
  for (int i = 0; i < 4; i++)
    #pragma unroll
    for (int e = 0; e < 4; e++){
      float p = 0.f;
      #pragma unroll
      for (int j = 0; j < 8; j++){
        acc[i][j][e] += bcol[j];
        p += acc[i][j][e] * acc[i][j][e];
      }
      p += __shfl_xor(p, 1); p += __shfl_xor(p, 2);
      p += __shfl_xor(p, 4); p += __shfl_xor(p, 8);
      if (fr == 0) rsum[(wr + i * 16 + fq * 4 + e) * 4 + (wid & 3)] = p;
    }
  __syncthreads();
  if (tid < 128){
    float ss = rsum[tid * 4] + rsum[tid * 4 + 1] + rsum[tid * 4 + 2] + rsum[tid * 4 + 3];
    invr[tid] = rsqrtf(ss + 1e-12f);
  }
  __syncthreads();
  #pragma unroll
  for (int i = 0; i < 4; i++)
    #pragma unroll
    for (int e = 0; e < 4; e++){
      float iv = invr[wr + i * 16 + fq * 4 + e];
      #pragma unroll
      for (int j = 0; j < 8; j++)
        acc[i][j][e] *= iv * gcol[j];
    }
  // invr fully consumed; trans may now overwrite everything.
  const int myhalf = wid >> 2;
  const int cbase = tid >> 3, pi = (tid & 7) * 4;
  #pragma unroll
  for (int q = 0; q < 4; q++){
    __syncthreads();                         // previous pass reads / invr reads done
    if (myhalf == (q >> 1)){
      #pragma unroll
      for (int ii = 0; ii < 2; ii++){
        const int i = (q & 1) * 2 + ii;
        const int ro = ii * 16 + fq * 4;
        #pragma unroll
        for (int j = 0; j < 8; j++){
          int col = wc + j * 16 + fr;
          *(f32x4*)&trans[col * 40 + ro] = acc[i][j];
        }
      }
    }
    __syncthreads();
    #pragma unroll
    for (int it = 0; it < 8; it++){
      int cc = it * 64 + cbase;
      f32x4 v = *(const f32x4*)&trans[cc * 40 + pi];
      *(f32x4*)(out + ((size_t)(z * 512 + cc)) * 4096 + m0 + q * 32 + pi) = v;
    }
  }
}

// ---- ctx split-K(8) partials (unchanged)
__global__ __launch_bounds__(256)
void gemm_ctx(const u16* __restrict__ kv, float* __restrict__ P,
              float* __restrict__ sden)
{
  constexpr int K = 512;
  const int z = blockIdx.z;
  const int tid = threadIdx.x;
  const int ar = tid >> 2, ac = (tid & 3) * 8;
  int bh = z >> 3, sp = z & 7, b = bh >> 3, h = bh & 7;
  const u16* A  = kv + (size_t)b * KV_B + (size_t)(h * 64) * 4096 + sp * 512;
  const u16* BT = kv + (size_t)b * KV_B + (size_t)(512 + h * 64) * 4096 + sp * 512;
  __shared__ u16 As[64 * 40];
  __shared__ u16 Bs[64 * 40];
  const int wid = tid >> 6, lane = tid & 63;
  const int wr = (wid >> 1) * 32, wc = (wid & 1) * 32;
  const int lr = lane & 15, kb = lane >> 4;
  f32x4 acc[2][2] = {};
  float ssum = 0.f;
  for (int k0 = 0; k0 < K; k0 += 32){
    short8 av = *(const short8*)(A + (size_t)ar * 4096 + k0 + ac);
    short8 ao;
    #pragma unroll
    for (int e = 0; e < 8; e++){
      float ev = __expf(b2f((u16)av[e]));
      ao[e] = (short)f2b(ev);
      ssum += ev;
    }
    *(short8*)(As + ar * 40 + ac) = ao;
    *(short8*)(Bs + ar * 40 + ac) = *(const short8*)(BT + (size_t)ar * 4096 + k0 + ac);
    __syncthreads();
    short8 a0 = *(const short8*)(As + (wr +      lr) * 40 + kb * 8);
    short8 a1 = *(const short8*)(As + (wr + 16 + lr) * 40 + kb * 8);
    short8 b0 = *(const short8*)(Bs + (wc +      lr) * 40 + kb * 8);
    short8 b1 = *(const short8*)(Bs + (wc + 16 + lr) * 40 + kb * 8);
    acc[0][0] = __builtin_amdgcn_mfma_f32_16x16x32_bf16(a0, b0, acc[0][0], 0, 0, 0);
    acc[0][1] = __builtin_amdgcn_mfma_f32_16x16x32_bf16(a0, b1, acc[0][1], 0, 0, 0);
    acc[1][0] = __builtin_amdgcn_mfma_f32_16x16x32_bf16(a1, b0, acc[1][0], 0, 0, 0);
    acc[1][1] = __builtin_amdgcn_mfma_f32_16x16x32_bf16(a1, b1, acc[1][1], 0, 0, 0);
    __syncthreads();
  }
  ssum += __shfl_xor(ssum, 1);
  ssum += __shfl_xor(ssum, 2);
  if ((tid & 3) == 0) atomicAdd(sden + b * 512 + h * 64 + ar, ssum);
  #pragma unroll
  for (int mi = 0; mi < 2; mi++)
    #pragma unroll
    for (int ni = 0; ni < 2; ni++)
      #pragma unroll
      for (int j = 0; j < 4; j++){
        int row = wr + mi * 16 + kb * 4 + j;
        int col = wc + ni * 16 + lr;
        P[(size_t)z * 4096 + (size_t)row * 64 + col] = acc[mi][ni][j];
      }
}

// ---- kctxw (unchanged)
__global__ __launch_bounds__(256)
void kctxw(const float* __restrict__ P, const float* __restrict__ sden,
           const u16* __restrict__ woutbf, u16* __restrict__ M)
{
  const int z = blockIdx.z;
  const int b = z >> 3, h = z & 7;
  const int m0 = blockIdx.y * 64;
  const int tid = threadIdx.x;
  __shared__ u16 As[64 * 72];
  __shared__ u16 Bs[64 * 72];
  {
    int r = tid >> 2, c0 = (tid & 3) * 16;
    const u16* wsrc = woutbf + (size_t)(m0 + r) * 512 + h * 64 + c0;
    *(short8*)(As + r * 72 + c0)     = *(const short8*)(wsrc);
    *(short8*)(As + r * 72 + c0 + 8) = *(const short8*)(wsrc + 8);
    float rs = 1.f / sden[b * 512 + h * 64 + r];
    const float* p = P + (size_t)z * 32768 + (size_t)r * 64 + c0;
    #pragma unroll
    for (int e = 0; e < 16; e++){
      float s = 0.f;
      #pragma unroll
      for (int sp = 0; sp < 8; sp++) s += p[e + sp * 4096];
      Bs[r * 72 + c0 + e] = f2b(s * rs);
    }
  }
  __syncthreads();
  const int wid = tid >> 6, lane = tid & 63;
  const int wr = (wid >> 1) * 32, wc = (wid & 1) * 32;
  const int lr = lane & 15, kb = lane >> 4;
  f32x4 acc[2][2] = {};
  #pragma unroll
  for (int k0 = 0; k0 < 64; k0 += 32){
    short8 a0 = *(const short8*)(As + (wr +      lr) * 72 + k0 + kb * 8);
    short8 a1 = *(const short8*)(As + (wr + 16 + lr) * 72 + k0 + kb * 8);
    short8 b0 = *(const short8*)(Bs + (wc +      lr) * 72 + k0 + kb * 8);
    short8 b1 = *(const short8*)(Bs + (wc + 16 + lr) * 72 + k0 + kb * 8);
    acc[0][0] = __builtin_amdgcn_mfma_f32_16x16x32_bf16(a0, b0, acc[0][0], 0, 0, 0);
    acc[0][1] = __builtin_amdgcn_mfma_f32_16x16x32_bf16(a0, b1, acc[0][1], 0, 0, 0);
    acc[1][0] = __builtin_amdgcn_mfma_f32_16x16x32_bf16(a1, b0, acc[1][0], 0, 0, 0);
    acc[1][1] = __builtin_amdgcn_mfma_f32_16x16x32_bf16(a1, b1, acc[1][1], 0, 0, 0);
  }
  #pragma unroll
  for (int mi = 0; mi < 2; mi++)
    #pragma unroll
    for (int ni = 0; ni < 2; ni++)
      #pragma unroll
      for (int j = 0; j < 4; j++){
        int row = m0 + wr + mi * 16 + kb * 4 + j;
        int col = wc + ni * 16 + lr;
        M[(size_t)b * 262144 + (size_t)row * 512 + h * 64 + col] = f2b(acc[mi][ni][j]);
      }
}

extern "C" void kernel_launch(void* const* d_in, const int* in_sizes, int n_in,
                              void* d_out, int out_size, void* d_ws, size_t ws_size,
                              hipStream_t stream)
{
  (void)in_sizes; (void)n_in; (void)out_size; (void)ws_size;
  const float* x    = (const float*)d_in[0];
  const float* g1   = (const float*)d_in[1];
  const float* wqkv = (const float*)d_in[2];
  const float* wout = (const float*)d_in[3];
  const float* bout = (const float*)d_in[4];
  const float* g2   = (const float*)d_in[5];
  float* out = (float*)d_out;
  char* ws = (char*)d_ws;

  u16*   xnT   = (u16*)(ws);                          // S1 (dead after kv+qT)
  float* P     = (float*)(ws);                        // S1+0, 8MB (after xnT dead)
  u16*   M     = (u16*)(ws + (size_t)8388608);        // S1+8M, 4MB
  u16*   qT    = (u16*)(ws + (size_t)33554432);       // S2
  u16*   kv    = (u16*)(ws + (size_t)67108864);       // S3
  u16*   wbf   = (u16*)(ws + (size_t)134217728);      // E: wq+wkv bf16 (1.5MB)
  u16*   wkvbf = wbf + (size_t)512 * 512;
  u16*   woutbf= (u16*)(ws + (size_t)135790592);      // 512KB
  float* sden  = (float*)(ws + (size_t)136314880);    // 16KB

  // 1) weights->bf16 (g1 folded) + fused rms1 (vectorized) -> xnT + zero sden
  kprep<<<2048, 256, 0, stream>>>(wqkv, wout, g1, wbf, woutbf, x, xnT, sden);
  // 2) kv_b = Wkv @ xn_b — proven r5/r12 kernel
  gemm_kv<<<dim3(32, 8, 8), 256, 0, stream>>>(wkvbf, xnT, kv);
  // 3) qT = softmax_d(xnT @ Wq^T)/8 — proven r10 256^2 kernel
  gemm_q<<<dim3(2, 128, 1), 512, 0, stream>>>(xnT, wbf, qT);
  // 4) ctx split-K(8) partials (unnormalized exp(k); sden accumulated inline)
  gemm_ctx<<<dim3(1, 1, 512), 256, 0, stream>>>(kv, P, sden);
  // 5) reduce partials, normalize by sden, fold W_out: M_b = Wout_h @ ctx_bh
  kctxw<<<dim3(1, 8, 64), 256, 0, stream>>>(P, sden, woutbf, M);
  // 6) fused: out2 = qT @ M_b^T + bias, rms2, transposed f32 store -> d_out
  gemm_outrms<<<dim3(32, 8), 512, 0, stream>>>(qT, M, bout, g2, out);
}

// Round 22
// 163.308 us; speedup vs baseline: 1.0137x; 1.0137x over previous
//
#include <hip/hip_runtime.h>

// LinearAttention on MI355X — round 22 = round 17 EXACT (best measured:
// 164.2us). Merged gemm_qkv (kv + qT/SMAX), kprep (weights+rms1 fused,
// vectorized), gemm_ctx split-K8 with inline sden, kctxw (reduce+Wout fold),
// gemm_outrms (out2+bias+rms2+transpose fused, no out2T buffer).
// ws: S1=0: xnT -> P(8MB) + M@+8M | S2=33.5M: qT | S3=67.1M: kv
//     E=134217728: wbf(1.5M) | woutbf@135790592 | sden@136314880 (16KB)

typedef unsigned short u16;
typedef __attribute__((ext_vector_type(8))) short short8;
typedef __attribute__((ext_vector_type(4))) short short4_t;
typedef __attribute__((ext_vector_type(4))) float f32x4;

static constexpr size_t XN_B = (size_t)512 * 4096;
static constexpr size_t KV_B = (size_t)1024 * 4096;
static constexpr float SQRT512 = 22.62741699796952f;

typedef const __attribute__((address_space(1))) unsigned int gu32;
typedef __attribute__((address_space(3))) unsigned int lu32;

__device__ __forceinline__ float b2f(u16 u){
  union { unsigned u; float f; } x; x.u = ((unsigned)u) << 16; return x.f;
}
__device__ __forceinline__ u16 f2b(float f){
  union { float f; unsigned u; } x; x.f = f;
  unsigned r = x.u + 0x7FFFu + ((x.u >> 16) & 1u);   // RNE
  return (u16)(r >> 16);
}
__device__ __forceinline__ void gl16(const u16* g, u16* l){
  __builtin_amdgcn_global_load_lds((gu32*)g, (lu32*)l, 16, 0, 0);
}

// ---- kprep: blocks 0-1023 convert weights (g1 folded into wqkv; blocks 0-15
//      also zero sden); blocks 1024-2047 fused rms1, f32x4-vectorized
__global__ __launch_bounds__(256)
void kprep(const float* __restrict__ wqkv, const float* __restrict__ wout,
           const float* __restrict__ g1, u16* __restrict__ dq, u16* __restrict__ dw,
           const float* __restrict__ x, u16* __restrict__ xnT,
           float* __restrict__ sden){
  __shared__ u16 lt[32][514];
  __shared__ float red4[256][4];
  __shared__ float invs[32];
  int bid = blockIdx.x;
  int t = threadIdx.x;
  if (bid < 1024){
    if (bid < 16) sden[bid * 256 + t] = 0.f;
    size_t i = ((size_t)bid * 256 + t) * 4;
    short4_t o;
    if (i < (size_t)786432){
      f32x4 v = *(const f32x4*)(wqkv + i);
      int c = (int)(i & 511);
      #pragma unroll
      for (int j = 0; j < 4; j++) o[j] = (short)f2b(v[j] * g1[c + j] * SQRT512);
      *(short4_t*)(dq + i) = o;
    } else {
      size_t off = i - 786432;
      f32x4 v = *(const f32x4*)(wout + off);
      #pragma unroll
      for (int j = 0; j < 4; j++) o[j] = (short)f2b(v[j]);
      *(short4_t*)(dw + off) = o;
    }
    return;
  }
  int pg0 = (bid - 1024) * 32;
  int b = pg0 >> 12, p0 = pg0 & 4095;
  int pxg = (t & 7) * 4;
  int chunk = t >> 3;
  const float* xp = x + (size_t)b * XN_B + p0 + pxg;
  f32x4 s = {0.f, 0.f, 0.f, 0.f};
  #pragma unroll 4
  for (int c = chunk * 16; c < chunk * 16 + 16; ++c){
    f32x4 v = *(const f32x4*)(xp + (size_t)c * 4096);
    #pragma unroll
    for (int j = 0; j < 4; j++){
      lt[pxg + j][c] = f2b(v[j]);
      s[j] += v[j] * v[j];
    }
  }
  *(f32x4*)red4[t] = s;
  __syncthreads();
  if (t < 32){
    int pg = t >> 2, pe = t & 3;
    float sum = 0.f;
    #pragma unroll
    for (int ch = 0; ch < 32; ch++) sum += red4[ch * 8 + pg][pe];
    invs[t] = rsqrtf(sum + 1e-12f);
  }
  __syncthreads();
  int px2 = t >> 3, c0 = (t & 7) * 8;
  float iv = invs[px2];
  u16* dst = xnT + (size_t)(pg0 + px2) * 512;
  #pragma unroll
  for (int j = 0; j < 8; j++){
    int c = c0 + j * 64;
    short8 o;
    #pragma unroll
    for (int e = 0; e < 8; e++) o[e] = (short)f2b(b2f(lt[px2][c + e]) * iv);
    *(short8*)(dst + c) = o;
  }
}

// ---- merged qT + kv GEMM. 128^2 tile, BK=64 dbuf, counted vmcnt(8), XOR
// swizzle. Blocks 0-2047: kv_b = Wkv @ xn_b. Blocks 2048-3071: qT + SMAX.
__global__ __launch_bounds__(256)
void gemm_qkv(const u16* __restrict__ Wkv, const u16* __restrict__ wq,
              const u16* __restrict__ xnT, u16* __restrict__ kvb,
              u16* __restrict__ qT)
{
  constexpr int NT = 8;
  const int bid = blockIdx.x;
  const u16* A; const u16* BT; u16* C;
  int m0, n0; size_t ldc; bool smax;
  if (bid < 2048){
    int ntile = bid & 31, mtile = (bid >> 5) & 7, z = bid >> 8;
    A = Wkv; BT = xnT + (size_t)z * XN_B; C = kvb + (size_t)z * KV_B;
    m0 = mtile * 128; n0 = ntile * 128; ldc = 4096; smax = false;
  } else {
    int idx = bid - 2048;
    int ntile = idx & 3, mtile = idx >> 2;
    A = xnT; BT = wq; C = qT;
    m0 = mtile * 128; n0 = ntile * 128; ldc = 512; smax = true;
  }
  __shared__ u16 As[2][128 * 64];
  __shared__ u16 Bs[2][128 * 64];
  const int tid = threadIdx.x;
  const int srow0 = tid >> 3;
  const int schunk = tid & 7;
  const int lane = tid & 63, wid = tid >> 6;
  const int wr = (wid >> 1) * 64, wc = (wid & 1) * 64;
  const int fr = lane & 15, fq = lane >> 4;
  f32x4 acc[4][4] = {};

  auto STAGE = [&](int s, int t){
    const int k0 = t * 64;
    #pragma unroll
    for (int r = 0; r < 4; r++){
      int row = r * 32 + srow0;
      int gj = (schunk ^ (row & 7)) * 8;
      gl16(A  + (size_t)(m0 + row) * 512 + k0 + gj, &As[s][0] + r * 2048 + tid * 8);
      gl16(BT + (size_t)(n0 + row) * 512 + k0 + gj, &Bs[s][0] + r * 2048 + tid * 8);
    }
  };

  STAGE(0, 0);
  int cur = 0;
  for (int t = 0; t < NT; t++){
    if (t + 1 < NT){
      STAGE(cur ^ 1, t + 1);
      asm volatile("s_waitcnt vmcnt(8)" ::: "memory");
    } else {
      asm volatile("s_waitcnt vmcnt(0)" ::: "memory");
    }
    __builtin_amdgcn_s_barrier();
    __builtin_amdgcn_sched_barrier(0);
    #pragma unroll
    for (int ks = 0; ks < 2; ks++){
      short8 a[4], b[4];
      #pragma unroll
      for (int i = 0; i < 4; i++){
        int ra = wr + i * 16 + fr;
        a[i] = *(const short8*)(&As[cur][0] + ra * 64 + ((ks * 4 + fq) ^ (ra & 7)) * 8);
        int rb = wc + i * 16 + fr;
        b[i] = *(const short8*)(&Bs[cur][0] + rb * 64 + ((ks * 4 + fq) ^ (rb & 7)) * 8);
      }
      #pragma unroll
      for (int i = 0; i < 4; i++)
        #pragma unroll
        for (int j = 0; j < 4; j++)
          acc[i][j] = __builtin_amdgcn_mfma_f32_16x16x32_bf16(a[i], b[j], acc[i][j], 0, 0, 0);
    }
    __builtin_amdgcn_sched_barrier(0);
    __builtin_amdgcn_s_barrier();
    cur ^= 1;
  }

  if (smax){
    #pragma unroll
    for (int i = 0; i < 4; i++)
      #pragma unroll
      for (int e = 0; e < 4; e++){
        float mx = fmaxf(fmaxf(acc[i][0][e], acc[i][1][e]),
                         fmaxf(acc[i][2][e], acc[i][3][e]));
        mx = fmaxf(mx, __shfl_xor(mx, 1));
        mx = fmaxf(mx, __shfl_xor(mx, 2));
        mx = fmaxf(mx, __shfl_xor(mx, 4));
        mx = fmaxf(mx, __shfl_xor(mx, 8));
        float p0 = __expf(acc[i][0][e] - mx);
        float p1 = __expf(acc[i][1][e] - mx);
        float p2 = __expf(acc[i][2][e] - mx);
        float p3 = __expf(acc[i][3][e] - mx);
        float s = p0 + p1 + p2 + p3;
        s += __shfl_xor(s, 1);
        s += __shfl_xor(s, 2);
        s += __shfl_xor(s, 4);
        s += __shfl_xor(s, 8);
        float r = 1.f / (s * 8.0f);
        acc[i][0][e] = p0 * r; acc[i][1][e] = p1 * r;
        acc[i][2][e] = p2 * r; acc[i][3][e] = p3 * r;
      }
  }
  #pragma unroll
  for (int i = 0; i < 4; i++)
    #pragma unroll
    for (int j = 0; j < 4; j++)
      #pragma unroll
      for (int e = 0; e < 4; e++){
        int row = m0 + wr + i * 16 + fq * 4 + e;
        int col = n0 + wc + j * 16 + fr;
        C[(size_t)row * ldc + col] = f2b(acc[i][j][e]);
      }
}

// ---- fused out2 GEMM + rms2: 128(px)x512(ch) tile, bias + row rms (f32)
// + LDS transpose + direct f32 [c][p] stores. out2T never materialized.
__global__ __launch_bounds__(512)
void gemm_outrms(const u16* __restrict__ qT, const u16* __restrict__ Mb,
                 const float* __restrict__ bias, const float* __restrict__ g2,
                 float* __restrict__ out)
{
  constexpr int NT = 16;
  const int mt = blockIdx.x, z = blockIdx.y;
  const u16* A  = qT + (size_t)z * 4096 * 512;
  const u16* BT = Mb + (size_t)z * 262144;
  const int m0 = mt * 128;

  __shared__ char smem[84480] __attribute__((aligned(16)));
  u16*   As    = (u16*)smem;
  u16*   Bs    = (u16*)(smem + 16384);
  float* trans = (float*)smem;
  float* rsum  = (float*)(smem + 81920);
  float* invr  = (float*)(smem + 83968);

  const int tid = threadIdx.x;
  const int lane = tid & 63, wid = tid >> 6;
  const int wr = (wid >> 2) * 64;
  const int wc = (wid & 3) * 128;
  const int fr = lane & 15, fq = lane >> 4;
  const int srow = tid >> 2, schunk = tid & 3;
  f32x4 acc[4][8] = {};

  auto STAGE = [&](int s, int t){
    const int k0 = t * 32;
    {
      int gj = (schunk ^ ((srow >> 1) & 3)) * 8;
      gl16(A + (size_t)(m0 + srow) * 512 + k0 + gj, As + s * 4096 + tid * 8);
    }
    #pragma unroll
    for (int r = 0; r < 4; r++){
      int row = r * 128 + srow;
      int gj = (schunk ^ ((row >> 1) & 3)) * 8;
      gl16(BT + (size_t)row * 512 + k0 + gj, Bs + s * 16384 + r * 4096 + tid * 8);
    }
  };

  STAGE(0, 0);
  int cur = 0;
  for (int t = 0; t < NT; t++){
    if (t + 1 < NT){
      STAGE(cur ^ 1, t + 1);
      asm volatile("s_waitcnt vmcnt(5)" ::: "memory");
    } else {
      asm volatile("s_waitcnt vmcnt(0)" ::: "memory");
    }
    __builtin_amdgcn_s_barrier();
    __builtin_amdgcn_sched_barrier(0);
    short8 a[4], b[8];
    #pragma unroll
    for (int i = 0; i < 4; i++){
      int ra = wr + i * 16 + fr;
      a[i] = *(const short8*)(As + cur * 4096 + ra * 32 + ((fq ^ ((ra >> 1) & 3)) * 8));
    }
    #pragma unroll
    for (int j = 0; j < 8; j++){
      int rb = wc + j * 16 + fr;
      b[j] = *(const short8*)(Bs + cur * 16384 + rb * 32 + ((fq ^ ((rb >> 1) & 3)) * 8));
    }
    #pragma unroll
    for (int i = 0; i < 4; i++)
      #pragma unroll
      for (int j = 0; j < 8; j++)
        acc[i][j] = __builtin_amdgcn_mfma_f32_16x16x32_bf16(a[i], b[j], acc[i][j], 0, 0, 0);
    __builtin_amdgcn_sched_barrier(0);
    __builtin_amdgcn_s_barrier();
    cur ^= 1;
  }

  float bcol[8], gcol[8];
  #pragma unroll
  for (int j = 0; j < 8; j++){
    int col = wc + j * 16 + fr;
    bcol[j] = bias[col];
    gcol[j] = g2[col] * SQRT512;
  }
  #pragma unroll
  for (int i = 0; i < 4; i++)
    #pragma unroll
    for (int e = 0; e < 4; e++){
      float p = 0.f;
      #pragma unroll
      for (int j = 0; j < 8; j++){
        acc[i][j][e] += bcol[j];
        p += acc[i][j][e] * acc[i][j][e];
      }
      p += __shfl_xor(p, 1); p += __shfl_xor(p, 2);
      p += __shfl_xor(p, 4); p += __shfl_xor(p, 8);
      if (fr == 0) rsum[(wr + i * 16 + fq * 4 + e) * 4 + (wid & 3)] = p;
    }
  __syncthreads();
  if (tid < 128){
    float ss = rsum[tid * 4] + rsum[tid * 4 + 1] + rsum[tid * 4 + 2] + rsum[tid * 4 + 3];
    invr[tid] = rsqrtf(ss + 1e-12f);
  }
  __syncthreads();
  #pragma unroll
  for (int i = 0; i < 4; i++)
    #pragma unroll
    for (int e = 0; e < 4; e++){
      float iv = invr[wr + i * 16 + fq * 4 + e];
      #pragma unroll
      for (int j = 0; j < 8; j++)
        acc[i][j][e] *= iv * gcol[j];
    }
  const int myhalf = wid >> 2;
  const int cbase = tid >> 3, pi = (tid & 7) * 4;
  #pragma unroll
  for (int q = 0; q < 4; q++){
    __syncthreads();
    if (myhalf == (q >> 1)){
      #pragma unroll
      for (int ii = 0; ii < 2; ii++){
        const int i = (q & 1) * 2 + ii;
        const int ro = ii * 16 + fq * 4;
        #pragma unroll
        for (int j = 0; j < 8; j++){
          int col = wc + j * 16 + fr;
          *(f32x4*)&trans[col * 40 + ro] = acc[i][j];
        }
      }
    }
    __syncthreads();
    #pragma unroll
    for (int it = 0; it < 8; it++){
      int cc = it * 64 + cbase;
      f32x4 v = *(const f32x4*)&trans[cc * 40 + pi];
      *(f32x4*)(out + ((size_t)(z * 512 + cc)) * 4096 + m0 + q * 32 + pi) = v;
    }
  }
}

// ---- ctx split-K(8) partials: P[z=bh*8+s][d][e] f32. Stages UNNORMALIZED
// exp(k); accumulates the row expsum during staging -> atomicAdd into sden.
__global__ __launch_bounds__(256)
void gemm_ctx(const u16* __restrict__ kv, float* __restrict__ P,
              float* __restrict__ sden)
{
  constexpr int K = 512;
  const int z = blockIdx.z;
  const int tid = threadIdx.x;
  const int ar = tid >> 2, ac = (tid & 3) * 8;
  int bh = z >> 3, sp = z & 7, b = bh >> 3, h = bh & 7;
  const u16* A  = kv + (size_t)b * KV_B + (size_t)(h * 64) * 4096 + sp * 512;
  const u16* BT = kv + (size_t)b * KV_B + (size_t)(512 + h * 64) * 4096 + sp * 512;
  __shared__ u16 As[64 * 40];
  __shared__ u16 Bs[64 * 40];
  const int wid = tid >> 6, lane = tid & 63;
  const int wr = (wid >> 1) * 32, wc = (wid & 1) * 32;
  const int lr = lane & 15, kb = lane >> 4;
  f32x4 acc[2][2] = {};
  float ssum = 0.f;
  for (int k0 = 0; k0 < K; k0 += 32){
    short8 av = *(const short8*)(A + (size_t)ar * 4096 + k0 + ac);
    short8 ao;
    #pragma unroll
    for (int e = 0; e < 8; e++){
      float ev = __expf(b2f((u16)av[e]));
      ao[e] = (short)f2b(ev);
      ssum += ev;
    }
    *(short8*)(As + ar * 40 + ac) = ao;
    *(short8*)(Bs + ar * 40 + ac) = *(const short8*)(BT + (size_t)ar * 4096 + k0 + ac);
    __syncthreads();
    short8 a0 = *(const short8*)(As + (wr +      lr) * 40 + kb * 8);
    short8 a1 = *(const short8*)(As + (wr + 16 + lr) * 40 + kb * 8);
    short8 b0 = *(const short8*)(Bs + (wc +      lr) * 40 + kb * 8);
    short8 b1 = *(const short8*)(Bs + (wc + 16 + lr) * 40 + kb * 8);
    acc[0][0] = __builtin_amdgcn_mfma_f32_16x16x32_bf16(a0, b0, acc[0][0], 0, 0, 0);
    acc[0][1] = __builtin_amdgcn_mfma_f32_16x16x32_bf16(a0, b1, acc[0][1], 0, 0, 0);
    acc[1][0] = __builtin_amdgcn_mfma_f32_16x16x32_bf16(a1, b0, acc[1][0], 0, 0, 0);
    acc[1][1] = __builtin_amdgcn_mfma_f32_16x16x32_bf16(a1, b1, acc[1][1], 0, 0, 0);
    __syncthreads();
  }
  ssum += __shfl_xor(ssum, 1);
  ssum += __shfl_xor(ssum, 2);
  if ((tid & 3) == 0) atomicAdd(sden + b * 512 + h * 64 + ar, ssum);
  #pragma unroll
  for (int mi = 0; mi < 2; mi++)
    #pragma unroll
    for (int ni = 0; ni < 2; ni++)
      #pragma unroll
      for (int j = 0; j < 4; j++){
        int row = wr + mi * 16 + kb * 4 + j;
        int col = wc + ni * 16 + lr;
        P[(size_t)z * 4096 + (size_t)row * 64 + col] = acc[mi][ni][j];
      }
}

// ---- kctxw: ctx[d][e] = (sum of 8 P splits)/sden[d] (bf16, in LDS), then
//      M_b[co][h*64+d] = sum_e Wout[co][h*64+e] * ctx[d][e]
__global__ __launch_bounds__(256)
void kctxw(const float* __restrict__ P, const float* __restrict__ sden,
           const u16* __restrict__ woutbf, u16* __restrict__ M)
{
  const int z = blockIdx.z;
  const int b = z >> 3, h = z & 7;
  const int m0 = blockIdx.y * 64;
  const int tid = threadIdx.x;
  __shared__ u16 As[64 * 72];
  __shared__ u16 Bs[64 * 72];
  {
    int r = tid >> 2, c0 = (tid & 3) * 16;
    const u16* wsrc = woutbf + (size_t)(m0 + r) * 512 + h * 64 + c0;
    *(short8*)(As + r * 72 + c0)     = *(const short8*)(wsrc);
    *(short8*)(As + r * 72 + c0 + 8) = *(const short8*)(wsrc + 8);
    float rs = 1.f / sden[b * 512 + h * 64 + r];
    const float* p = P + (size_t)z * 32768 + (size_t)r * 64 + c0;
    #pragma unroll
    for (int e = 0; e < 16; e++){
      float s = 0.f;
      #pragma unroll
      for (int sp = 0; sp < 8; sp++) s += p[e + sp * 4096];
      Bs[r * 72 + c0 + e] = f2b(s * rs);
    }
  }
  __syncthreads();
  const int wid = tid >> 6, lane = tid & 63;
  const int wr = (wid >> 1) * 32, wc = (wid & 1) * 32;
  const int lr = lane & 15, kb = lane >> 4;
  f32x4 acc[2][2] = {};
  #pragma unroll
  for (int k0 = 0; k0 < 64; k0 += 32){
    short8 a0 = *(const short8*)(As + (wr +      lr) * 72 + k0 + kb * 8);
    short8 a1 = *(const short8*)(As + (wr + 16 + lr) * 72 + k0 + kb * 8);
    short8 b0 = *(const short8*)(Bs + (wc +      lr) * 72 + k0 + kb * 8);
    short8 b1 = *(const short8*)(Bs + (wc + 16 + lr) * 72 + k0 + kb * 8);
    acc[0][0] = __builtin_amdgcn_mfma_f32_16x16x32_bf16(a0, b0, acc[0][0], 0, 0, 0);
    acc[0][1] = __builtin_amdgcn_mfma_f32_16x16x32_bf16(a0, b1, acc[0][1], 0, 0, 0);
    acc[1][0] = __builtin_amdgcn_mfma_f32_16x16x32_bf16(a1, b0, acc[1][0], 0, 0, 0);
    acc[1][1] = __builtin_amdgcn_mfma_f32_16x16x32_bf16(a1, b1, acc[1][1], 0, 0, 0);
  }
  #pragma unroll
  for (int mi = 0; mi < 2; mi++)
    #pragma unroll
    for (int ni = 0; ni < 2; ni++)
      #pragma unroll
      for (int j = 0; j < 4; j++){
        int row = m0 + wr + mi * 16 + kb * 4 + j;
        int col = wc + ni * 16 + lr;
        M[(size_t)b * 262144 + (size_t)row * 512 + h * 64 + col] = f2b(acc[mi][ni][j]);
      }
}

extern "C" void kernel_launch(void* const* d_in, const int* in_sizes, int n_in,
                              void* d_out, int out_size, void* d_ws, size_t ws_size,
                              hipStream_t stream)
{
  (void)in_sizes; (void)n_in; (void)out_size; (void)ws_size;
  const float* x    = (const float*)d_in[0];
  const float* g1   = (const float*)d_in[1];
  const float* wqkv = (const float*)d_in[2];
  const float* wout = (const float*)d_in[3];
  const float* bout = (const float*)d_in[4];
  const float* g2   = (const float*)d_in[5];
  float* out = (float*)d_out;
  char* ws = (char*)d_ws;

  u16*   xnT   = (u16*)(ws);                          // S1 (dead after gemm_qkv)
  float* P     = (float*)(ws);                        // S1+0, 8MB (after xnT dead)
  u16*   M     = (u16*)(ws + (size_t)8388608);        // S1+8M, 4MB
  u16*   qT    = (u16*)(ws + (size_t)33554432);       // S2
  u16*   kv    = (u16*)(ws + (size_t)67108864);       // S3
  u16*   wbf   = (u16*)(ws + (size_t)134217728);      // E: wq+wkv bf16 (1.5MB)
  u16*   wkvbf = wbf + (size_t)512 * 512;
  u16*   woutbf= (u16*)(ws + (size_t)135790592);      // 512KB
  float* sden  = (float*)(ws + (size_t)136314880);    // 16KB

  // 1) weights->bf16 (g1 folded) + fused rms1 (vectorized) -> xnT + zero sden
  kprep<<<2048, 256, 0, stream>>>(wqkv, wout, g1, wbf, woutbf, x, xnT, sden);
  // 2) merged: kv_b = Wkv @ xn_b (blocks 0-2047) + qT = softmax_d(xnT@Wq^T)/8
  gemm_qkv<<<3072, 256, 0, stream>>>(wkvbf, wbf, xnT, kv, qT);
  // 3) ctx split-K(8) partials (unnormalized exp(k); sden accumulated inline)
  gemm_ctx<<<dim3(1, 1, 512), 256, 0, stream>>>(kv, P, sden);
  // 4) reduce partials, normalize by sden, fold W_out: M_b = Wout_h @ ctx_bh
  kctxw<<<dim3(1, 8, 64), 256, 0, stream>>>(P, sden, woutbf, M);
  // 5) fused: out2 = qT @ M_b^T + bias, rms2, transposed f32 store -> d_out
  gemm_outrms<<<dim3(32, 8), 512, 0, stream>>>(qT, M, bout, g2, out);
}